// Round 8
// baseline (89.214 us; speedup 1.0000x reference)
//
#include <hip/hip_runtime.h>

// SpectralPooling via split-bf16 MFMA.
// y = A x_D A x_H A x_W x, A = 48x64 composed (truncate32 + iDCT48) matrix.
// All stages v_mfma_f32_16x16x32_bf16. Layouts (m89): A-op row=lane&15,
// k=8*(lane>>4)+j. B-op col=lane&15, same k. D: col=lane&15, row=4*(lane>>4)+reg.
// r7: k1 owns a d-group of 8 (transpose done in k1 registers); y2 layout
// [bc][dg=8][a1=48][a2=48][dd=8] bf16 so k2's k=d fragment is one b128 load.
// k2 has no LDS/barrier. XCD-pinned bc for y2 L2 locality; NT hints.

typedef __attribute__((ext_vector_type(8))) short short8;
typedef __attribute__((ext_vector_type(4))) float f32x4;
typedef __attribute__((ext_vector_type(4))) unsigned int u32x4;
typedef __attribute__((ext_vector_type(2))) unsigned int u32x2;

static __device__ __forceinline__ unsigned short f2bf(float f) {
    unsigned int u = __float_as_uint(f);
    u += 0x7fffu + ((u >> 16) & 1u);          // RNE
    return (unsigned short)(u >> 16);
}
static __device__ __forceinline__ float bf2f(unsigned short h) {
    return __uint_as_float(((unsigned int)h) << 16);
}

// Table: tbl[s][ks][t][lane][j]: split_s(At[k][a]), k=8*(lane>>4)+j+32*ks,
// a=16*t+(lane&15). Serves A-op and B-op roles identically.
static __device__ __forceinline__ short8 ldtbl(const unsigned short* __restrict__ tbl,
                                               int s, int ks, int t, int l) {
    return *(const short8*)(tbl + (unsigned)((((s * 2 + ks) * 3 + t) * 64 + l) * 8));
}

__global__ __launch_bounds__(256) void gen_tbl(unsigned short* __restrict__ tbl) {
    int i = blockIdx.x * 256 + threadIdx.x;     // 0..3071
    int j = i & 7;
    int lane = (i >> 3) & 63;
    int tks = i >> 9;                           // ks*3 + t
    int t = tks % 3, ks = tks / 3;
    int k = 8 * (lane >> 4) + j + 32 * ks;      // 0..63
    int a = 16 * t + (lane & 15);               // 0..47
    const float PI = 3.14159265358979323846f;
    const float s48 = 0.20412414523193150818f;  // sqrt(2/48)
    const float s64 = 0.17677669529663688110f;  // sqrt(2/64)
    float s = 0.f;
    for (int kk = 0; kk < 32; ++kk) {
        int m48 = ((2 * a + 1) * kk) % 192;     // exact angle reduction mod 4N
        int m64 = ((2 * k + 1) * kk) % 256;
        float c48 = __cosf(PI * (float)m48 / 96.0f) * s48;
        float c64 = __cosf(PI * (float)m64 / 128.0f) * s64;
        if (kk == 0) { c48 *= 0.70710678118654752440f; c64 *= 0.70710678118654752440f; }
        s += c48 * c64;
    }
    unsigned short hi = f2bf(s);
    unsigned short lo = f2bf(s - bf2f(hi));
    tbl[i] = hi;            // s=0 slab
    tbl[i + 3072] = lo;     // s=1 slab
}

// y2 strides in u16: dd=1, a2=8, a1=384, dg=18432, bc=147456.

// ---------------- K1: per (bc, dg): 8 slices, W then H, pack dd in regs ------
#define SC_S 72   // u16 row stride: 144 B rows (16B-aligned), b128 reads clean
__global__ __launch_bounds__(256) void k1_wh(const float* __restrict__ x,
                                             const unsigned short* __restrict__ tbl,
                                             unsigned short* __restrict__ y2) {
    __shared__ unsigned short sC[48 * SC_S];   // C1^T [a2][h], bf16, reused per dd

    const int tid = threadIdx.x;
    const int blk = blockIdx.x;                 // 1024 = 8 xcd * 16 bc_lo * 8 dg
    const int xcd = blk & 7;
    const int rest = blk >> 3;                  // 0..127
    const int bc = xcd * 16 + (rest & 15);
    const int dg = rest >> 4;                   // 0..7
    const int g = __builtin_amdgcn_readfirstlane(tid >> 6);
    const int l = tid & 63;
    const int r = l & 15;
    const int kq = l >> 4;

    u32x4 ob[3][4];                             // [tile][rr] -> 8 dd u16 packed
    f32x4 z = {0.f, 0.f, 0.f, 0.f};

    #pragma unroll
    for (int dd = 0; dd < 8; ++dd) {
        // ---- stage W: C1[h][a2] = sum_w x[h][w]*At[w][a2]; wave g: h in [16g,16g+16)
        f32x4 acc0 = z, acc1 = z, acc2 = z;
        const float* xb = x + (unsigned)((bc * 64 + dg * 8 + dd) * 4096
                                         + (16 * g + r) * 64 + kq * 8);
        #pragma unroll
        for (int ks = 0; ks < 2; ++ks) {
            f32x4 xa = __builtin_nontemporal_load((const f32x4*)(xb + 32 * ks));
            f32x4 xc = __builtin_nontemporal_load((const f32x4*)(xb + 32 * ks + 4));
            float v[8] = {xa[0], xa[1], xa[2], xa[3], xc[0], xc[1], xc[2], xc[3]};
            short8 xh, xl;
            #pragma unroll
            for (int j = 0; j < 8; ++j) {
                unsigned int u = __float_as_uint(v[j]);           // truncation split
                float rem = v[j] - __uint_as_float(u & 0xffff0000u);
                xh[j] = (short)(u >> 16);
                xl[j] = (short)(__float_as_uint(rem) >> 16);
            }
            #pragma unroll
            for (int t = 0; t < 3; ++t) {
                short8 wh = ldtbl(tbl, 0, ks, t, l);
                f32x4 a = (t == 0) ? acc0 : (t == 1) ? acc1 : acc2;
                a = __builtin_amdgcn_mfma_f32_16x16x32_bf16(xh, wh, a, 0, 0, 0);
                a = __builtin_amdgcn_mfma_f32_16x16x32_bf16(xl, wh, a, 0, 0, 0);
                if (t == 0) acc0 = a; else if (t == 1) acc1 = a; else acc2 = a;
            }
        }
        // store C1^T bf16 to LDS: lane holds C1[h=16g+4kq+rr][a2=16t+r]
        #pragma unroll
        for (int t = 0; t < 3; ++t) {
            f32x4 a = (t == 0) ? acc0 : (t == 1) ? acc1 : acc2;
            u32x2 pk;
            pk[0] = (unsigned int)f2bf(a[0]) | ((unsigned int)f2bf(a[1]) << 16);
            pk[1] = (unsigned int)f2bf(a[2]) | ((unsigned int)f2bf(a[3]) << 16);
            *(u32x2*)&sC[(16 * t + r) * SC_S + 16 * g + 4 * kq] = pk;
        }
        __syncthreads();

        // ---- stage H (swapped): C2[a2][a1] = sum_h C1[h][a2]*At[h][a1]
        // A-op = one b128 from sC; D row(4kq+rr)=a2-local.
        #define LOADA(m, ks) (*(const short8*)&sC[(16 * (m) + r) * SC_S + 8 * kq + 32 * (ks)])
        if (g < 3) {
            // wave g: tiles (m=0,n=g),(m=1,n=g) -> slots 0,1
            f32x4 c0 = z, c1 = z;
            #pragma unroll
            for (int ks = 0; ks < 2; ++ks) {
                short8 ah = ldtbl(tbl, 0, ks, g, l);
                c0 = __builtin_amdgcn_mfma_f32_16x16x32_bf16(LOADA(0, ks), ah, c0, 0, 0, 0);
                c1 = __builtin_amdgcn_mfma_f32_16x16x32_bf16(LOADA(1, ks), ah, c1, 0, 0, 0);
            }
            #pragma unroll
            for (int rr = 0; rr < 4; ++rr) {
                unsigned int b0 = f2bf(c0[rr]), b1 = f2bf(c1[rr]);
                if ((dd & 1) == 0) { ob[0][rr][dd >> 1] = b0;  ob[1][rr][dd >> 1] = b1; }
                else { ob[0][rr][dd >> 1] |= b0 << 16;  ob[1][rr][dd >> 1] |= b1 << 16; }
            }
        } else {
            // wave 3: row m=2, columns n=0..2 -> slots 0..2 (A-frag shared)
            f32x4 t0 = z, t1 = z, t2 = z;
            #pragma unroll
            for (int ks = 0; ks < 2; ++ks) {
                short8 ca = LOADA(2, ks);
                t0 = __builtin_amdgcn_mfma_f32_16x16x32_bf16(ca, ldtbl(tbl, 0, ks, 0, l), t0, 0, 0, 0);
                t1 = __builtin_amdgcn_mfma_f32_16x16x32_bf16(ca, ldtbl(tbl, 0, ks, 1, l), t1, 0, 0, 0);
                t2 = __builtin_amdgcn_mfma_f32_16x16x32_bf16(ca, ldtbl(tbl, 0, ks, 2, l), t2, 0, 0, 0);
            }
            #pragma unroll
            for (int rr = 0; rr < 4; ++rr) {
                unsigned int b0 = f2bf(t0[rr]), b1 = f2bf(t1[rr]), b2 = f2bf(t2[rr]);
                if ((dd & 1) == 0) {
                    ob[0][rr][dd >> 1] = b0; ob[1][rr][dd >> 1] = b1; ob[2][rr][dd >> 1] = b2;
                } else {
                    ob[0][rr][dd >> 1] |= b0 << 16; ob[1][rr][dd >> 1] |= b1 << 16; ob[2][rr][dd >> 1] |= b2 << 16;
                }
            }
        }
        __syncthreads();   // protect sC before next dd overwrites
    }

    // ---- write y2[bc][dg][a1][a2][dd]: lane writes 64 B contiguous per tile
    unsigned short* yo = y2 + (unsigned)(bc * 147456 + dg * 18432);
    if (g < 3) {
        #pragma unroll
        for (int t = 0; t < 2; ++t)          // (m=t, n=g)
            #pragma unroll
            for (int rr = 0; rr < 4; ++rr)
                *(u32x4*)(yo + (unsigned)((16 * g + r) * 384 + (16 * t + 4 * kq + rr) * 8)) = ob[t][rr];
    } else {
        #pragma unroll
        for (int t = 0; t < 3; ++t)          // (m=2, n=t)
            #pragma unroll
            for (int rr = 0; rr < 4; ++rr)
                *(u32x4*)(yo + (unsigned)((16 * t + r) * 384 + (32 + 4 * kq + rr) * 8)) = ob[t][rr];
    }
}

// ---------------- K2: D-transform, no LDS ----------------
// out[bc][a0][a1][a2] = sum_d y2[bc][d][a1][a2] * At[d][a0]
// A-op = y2 frag (row=a2-tile, k=d): ONE b128 at [bc][kq+4ks][a1][16m+r][0..8).
__global__ __launch_bounds__(256) void k2_d(const unsigned short* __restrict__ y2,
                                            const unsigned short* __restrict__ tbl,
                                            float* __restrict__ out) {
    const int tid = threadIdx.x;
    const int blk = blockIdx.x;                 // 1536 = 8 xcd * 16 bc_lo * 12 quad
    const int xcd = blk & 7;
    const int rest = blk >> 3;                  // 0..191
    const int bc = xcd * 16 + rest / 12;
    const int quad = rest % 12;
    const int g = __builtin_amdgcn_readfirstlane(tid >> 6);
    const int l = tid & 63;
    const int r = l & 15;
    const int kq = l >> 4;
    const int a1 = quad * 4 + g;

    const unsigned short* yb = y2 + (unsigned)(bc * 147456 + a1 * 384);

    short8 th[2][3], tl[2][3];                  // constant table, L1-hot
    #pragma unroll
    for (int ks = 0; ks < 2; ++ks)
        #pragma unroll
        for (int n = 0; n < 3; ++n) {
            th[ks][n] = ldtbl(tbl, 0, ks, n, l);
            tl[ks][n] = ldtbl(tbl, 1, ks, n, l);
        }

    f32x4 z = {0.f, 0.f, 0.f, 0.f};
    f32x4 acc[3][3];
    #pragma unroll
    for (int m = 0; m < 3; ++m)
        #pragma unroll
        for (int n = 0; n < 3; ++n) acc[m][n] = z;

    #pragma unroll
    for (int m = 0; m < 3; ++m)
        #pragma unroll
        for (int ks = 0; ks < 2; ++ks) {
            // A-frag: row=a2=16m+r, k=d=(kq+4ks)*8+j : contiguous 16 B
            short8 ya = *(const short8*)(yb + (unsigned)((kq + 4 * ks) * 18432 + (16 * m + r) * 8));
            #pragma unroll
            for (int n = 0; n < 3; ++n) {
                acc[m][n] = __builtin_amdgcn_mfma_f32_16x16x32_bf16(ya, th[ks][n], acc[m][n], 0, 0, 0);
                acc[m][n] = __builtin_amdgcn_mfma_f32_16x16x32_bf16(ya, tl[ks][n], acc[m][n], 0, 0, 0);
            }
        }

    // store: out[a0=16n+r][a1][a2=16m+4kq+rr], NT (never re-read)
    #pragma unroll
    for (int m = 0; m < 3; ++m)
        #pragma unroll
        for (int n = 0; n < 3; ++n) {
            f32x4 v = acc[m][n];
            float* dst = out + ((size_t)(bc * 48 + 16 * n + r) * 48 + a1) * 48 + 16 * m + 4 * kq;
            __builtin_nontemporal_store(v, (f32x4*)dst);
        }
}

extern "C" void kernel_launch(void* const* d_in, const int* in_sizes, int n_in,
                              void* d_out, int out_size, void* d_ws, size_t ws_size,
                              hipStream_t stream) {
    const float* x = (const float*)d_in[0];
    float* out = (float*)d_out;

    unsigned short* tbl = (unsigned short*)d_ws;                     // 12 KiB
    unsigned short* y2 = (unsigned short*)((char*)d_ws + 65536);     // 36.75 MiB bf16

    gen_tbl<<<12, 256, 0, stream>>>(tbl);
    k1_wh<<<128 * 8, 256, 0, stream>>>(x, tbl, y2);
    k2_d<<<128 * 12, 256, 0, stream>>>(y2, tbl, out);
}